// Round 7
// baseline (195.027 us; speedup 1.0000x reference)
//
#include <hip/hip_runtime.h>
#include <math.h>

#define BDIM 64
#define HDIM 512
#define WDIM 512
#define KW   31
#define PAD  15
#define INV_KK (1.0f / 961.0f)
#define TH   64                       // output rows per block
#define BAND 256                      // columns per block
#define NPIX ((size_t)BDIM * HDIM * WDIM)

// acc[0]: bce sum; acc[1..64]: inter[b]; acc[65..128]: union[b]
#define NACC 129

__global__ void zero_acc_kernel(double* acc) {
    int i = threadIdx.x;
    if (i < NACC) acc[i] = 0.0;
}

// ---- DPP helpers: VALU cross-lane (single v_add_f32_dpp each) -----------
template<int CTRL, int RMASK>
__device__ __forceinline__ float dpp_add(float p) {
    int t = __builtin_amdgcn_update_dpp(0, __builtin_bit_cast(int, p),
                                        CTRL, RMASK, 0xf, true);
    return p + __builtin_bit_cast(float, t);
}

// inclusive prefix sum over 64 lanes
__device__ __forceinline__ float wave_iscan(float p) {
    p = dpp_add<0x111, 0xf>(p);   // row_shr:1
    p = dpp_add<0x112, 0xf>(p);   // row_shr:2
    p = dpp_add<0x114, 0xf>(p);   // row_shr:4
    p = dpp_add<0x118, 0xf>(p);   // row_shr:8
    p = dpp_add<0x142, 0xa>(p);   // row_bcast:15 -> rows 1,3
    p = dpp_add<0x143, 0xc>(p);   // row_bcast:31 -> rows 2,3
    return p;
}

// inclusive prefix valid through lane 31 (we only use lanes 0..29)
__device__ __forceinline__ float wave_iscan30(float p) {
    p = dpp_add<0x111, 0xf>(p);
    p = dpp_add<0x112, 0xf>(p);
    p = dpp_add<0x114, 0xf>(p);
    p = dpp_add<0x118, 0xf>(p);
    p = dpp_add<0x142, 0xa>(p);
    return p;
}

// lane i <- lane i-1 (lane 0 -> 0)
__device__ __forceinline__ float wave_shr1(float p) {
    int t = __builtin_amdgcn_update_dpp(0, __builtin_bit_cast(int, p),
                                        0x138 /*WAVE_SHR1*/, 0xf, 0xf, true);
    return __builtin_bit_cast(float, t);
}

// Block = 256 threads = 4 waves over a 256-col band, 64 output rows.
// 1024 blocks -> 4 blocks/CU (LDS 33KB) -> 4 waves/SIMD.
// Horizontal 31-box: per-wave DPP prefix scans over redundant +/-15 halo;
// divergent edge handling via clamped column + 0/1 scale (no exec masks).
// Vertical 31-box: LDS ring (thread-private slots, no barriers), ring reads
// prefetched 2 rows ahead; global loads prefetched 4 rows ahead.
// Warmup (30 rows, no emit) and steady (64 rows, emit always) are split so
// the steady loop has no per-row emit guards.
__global__ __launch_bounds__(256, 4)
void fused_kernel(const float* __restrict__ pred,
                  const float* __restrict__ mask,
                  double* __restrict__ acc) {
    __shared__ float ring[32][BAND];  // 32 KiB
    __shared__ float red[3][4];

    const int b    = blockIdx.x;
    const int y0   = blockIdx.y * TH;
    const int tid  = threadIdx.x;
    const int lane = tid & 63;
    const int wv   = tid >> 6;
    const int x    = blockIdx.z * BAND + tid;        // output column
    const int s    = blockIdx.z * BAND + wv * 64;    // strip start column

    const float* mbase = mask + (size_t)b * HDIM * WDIM;
    const float* pbase = pred + (size_t)b * HDIM * WDIM;

    // halo columns: clamp + 0/1 scale replaces divergent predication
    int acol = s - 15 + lane;                // positions 0..63
    int bcol = s + 49 + lane;                // positions 64..93 (lanes 0..29)
    const float ascale = (acol >= 0 && acol < WDIM) ? 1.f : 0.f;
    const float bscale = (lane < 30 && bcol < WDIM) ? 1.f : 0.f;
    acol = min(max(acol, 0), WDIM - 1);
    bcol = min(max(bcol, 0), WDIM - 1);
    const int hi_lane = (lane + 30) & 63;

    const int tstart = y0 - PAD;
    const int tfirst = y0 + PAD;             // first emit row index t
    const int tend   = y0 + TH - 1 + PAD;    // last row index t

    float vs = 0.f;
    float bce_acc = 0.f, inter_acc = 0.f, uni_acc = 0.f;

    // zero the ring slot that the first steady row "subtracts"
    ring[(y0 + 16) & 31][tid] = 0.f;         // thread-private, no sync needed

    auto load_halo = [&](int t, float& A, float& B) {
        if ((unsigned)t < (unsigned)HDIM && t <= tend) {  // wave-uniform
            const float* rp = mbase + (size_t)t * WDIM;
            A = rp[acol] * ascale;
            B = rp[bcol] * bscale;
        } else { A = 0.f; B = 0.f; }
    };
    auto load_emit = [&](int t, float& M, float& P) {
        if (t <= tend) {                                   // wave-uniform
            const size_t off = (size_t)(t - PAD) * WDIM + x;
            M = mbase[off];
            P = pbase[off];
        } else { M = 0.f; P = 0.f; }
    };
    auto hscan = [&](float A, float B) -> float {
        float pa = wave_iscan(A);            // prefix over positions 0..63
        float pb = wave_iscan30(B);          // prefix over positions 64..93
        const float atot = __builtin_bit_cast(float,
            __builtin_amdgcn_readlane(__builtin_bit_cast(int, pa), 63));
        const float v1 = __shfl(pa, hi_lane);
        const float v2 = __shfl(pb, hi_lane);
        const float Phi = (lane <= 33) ? v1 : (atot + v2);
        const float Plo = wave_shr1(pa);
        return Phi - Plo;                    // 31-box at col s+lane
    };
    auto emit = [&](float M, float P) {
        const float box  = vs * INV_KK;
        const float weit = 1.f + 5.f * fabsf(box - M);
        const float e1   = __expf(-fabsf(P));
        const float den  = __builtin_amdgcn_rcpf(1.f + e1);
        const float sp   = ((P >= 0.f) ? 1.f : e1) * den;   // sigmoid(P)
        const float bce  = fmaxf(P, 0.f) - P * M + __logf(1.f + e1);
        bce_acc   += bce;
        inter_acc += sp * M * weit;
        uni_acc   += (sp + M) * weit;
    };

    // ---- prime halo pipeline: rows tstart..tstart+3 ----
    float cA0, cB0, cA1, cB1, nA0, nB0, nA1, nB1;
    load_halo(tstart,     cA0, cB0);
    load_halo(tstart + 1, cA1, cB1);
    load_halo(tstart + 2, nA0, nB0);
    load_halo(tstart + 3, nA1, nB1);
    // ---- prime emit pipeline: steady rows tfirst..tfirst+3 ----
    float cM0, cP0, cM1, cP1, nM0, nP0, nM1, nP1;
    load_emit(tfirst,     cM0, cP0);
    load_emit(tfirst + 1, cM1, cP1);
    load_emit(tfirst + 2, nM0, nP0);
    load_emit(tfirst + 3, nM1, nP1);

    // ---- warmup: rows tstart..tfirst-1 (30 rows, no emit) ----
    for (int t = tstart; t < tfirst; t += 2) {
        float fA0, fB0, fA1, fB1;
        load_halo(t + 4, fA0, fB0);
        load_halo(t + 5, fA1, fB1);
        {
            const float h = hscan(cA0, cB0);
            vs += h;
            ring[t & 31][tid] = h;
        }
        {
            const float h = hscan(cA1, cB1);
            vs += h;
            ring[(t + 1) & 31][tid] = h;
        }
        cA0 = nA0; cB0 = nB0; cA1 = nA1; cB1 = nB1;
        nA0 = fA0; nB0 = fB0; nA1 = fA1; nB1 = fB1;
    }

    // ring values for the first steady pair
    float rr0 = 0.f;                               // zeroed slot
    float rr1 = ring[(tfirst + 2) & 31][tid];      // row tfirst+1 - 31

    // ---- steady: rows tfirst..tend (64 rows, emit always) ----
#pragma unroll 2
    for (int t = tfirst; t < tend; t += 2) {
        float fA0, fB0, fA1, fB1, fM0, fP0, fM1, fP1;
        load_halo(t + 4, fA0, fB0);
        load_halo(t + 5, fA1, fB1);
        load_emit(t + 4, fM0, fP0);
        load_emit(t + 5, fM1, fP1);

        // ring prefetch for rows t+2, t+3 (slots overwritten only later)
        const float pr0 = ring[(t + 3) & 31][tid];
        const float pr1 = ring[(t + 4) & 31][tid];

        {
            const float h = hscan(cA0, cB0);
            vs += h - rr0;
            ring[t & 31][tid] = h;
            emit(cM0, cP0);
        }
        {
            const float h = hscan(cA1, cB1);
            vs += h - rr1;
            ring[(t + 1) & 31][tid] = h;
            emit(cM1, cP1);
        }

        cA0 = nA0; cB0 = nB0; cA1 = nA1; cB1 = nB1;
        cM0 = nM0; cP0 = nP0; cM1 = nM1; cP1 = nP1;
        nA0 = fA0; nB0 = fB0; nA1 = fA1; nB1 = fB1;
        nM0 = fM0; nP0 = fP0; nM1 = fM1; nP1 = fP1;
        rr0 = pr0; rr1 = pr1;
    }

    // ---- block reduction (4 waves) ----
#pragma unroll
    for (int off = 32; off > 0; off >>= 1) {
        bce_acc   += __shfl_down(bce_acc, off);
        inter_acc += __shfl_down(inter_acc, off);
        uni_acc   += __shfl_down(uni_acc, off);
    }
    if (lane == 0) {
        red[0][wv] = bce_acc;
        red[1][wv] = inter_acc;
        red[2][wv] = uni_acc;
    }
    __syncthreads();
    if (threadIdx.x == 0) {
        float bs = 0.f, is = 0.f, us = 0.f;
#pragma unroll
        for (int w = 0; w < 4; ++w) { bs += red[0][w]; is += red[1][w]; us += red[2][w]; }
        atomicAdd(&acc[0],      (double)bs);
        atomicAdd(&acc[1 + b],  (double)is);
        atomicAdd(&acc[65 + b], (double)us);
    }
}

__global__ void finalize_kernel(const double* __restrict__ acc, float* __restrict__ out) {
    const int b = threadIdx.x;   // one wave
    double inter = acc[1 + b];
    double uni   = acc[65 + b];
    double wiou  = 1.0 - (inter + 1.0) / (uni - inter + 1.0);
#pragma unroll
    for (int off = 32; off > 0; off >>= 1) wiou += __shfl_down(wiou, off);
    if (b == 0) {
        double wbce = acc[0] / (double)NPIX;
        out[0] = (float)(wbce + wiou / (double)BDIM);
    }
}

extern "C" void kernel_launch(void* const* d_in, const int* in_sizes, int n_in,
                              void* d_out, int out_size, void* d_ws, size_t ws_size,
                              hipStream_t stream) {
    const float* pred = (const float*)d_in[0];
    const float* mask = (const float*)d_in[1];
    float* out = (float*)d_out;
    double* acc = (double*)d_ws;

    zero_acc_kernel<<<1, 256, 0, stream>>>(acc);

    dim3 grid(BDIM, HDIM / TH, WDIM / BAND);
    fused_kernel<<<grid, 256, 0, stream>>>(pred, mask, acc);

    finalize_kernel<<<1, 64, 0, stream>>>(acc, out);
}

// Round 8
// 192.985 us; speedup vs baseline: 1.0106x; 1.0106x over previous
//
#include <hip/hip_runtime.h>
#include <hip/hip_fp16.h>
#include <math.h>

#define BDIM 64
#define HDIM 512
#define WDIM 512
#define INV_KK (1.0f / 961.0f)
#define NPIX ((size_t)BDIM * HDIM * WDIM)

// acc[0]: bce sum; acc[1..64]: inter[b]; acc[65..128]: union[b]
#define NACC 129

__global__ void zero_acc_kernel(double* acc) {
    int i = threadIdx.x;
    if (i < NACC) acc[i] = 0.0;
}

// ---- DPP helpers ---------------------------------------------------------
template<int CTRL, int RMASK>
__device__ __forceinline__ float dpp_add(float p) {
    int t = __builtin_amdgcn_update_dpp(0, __builtin_bit_cast(int, p),
                                        CTRL, RMASK, 0xf, true);
    return p + __builtin_bit_cast(float, t);
}
__device__ __forceinline__ float wave_iscan(float p) {   // 64-lane inclusive
    p = dpp_add<0x111, 0xf>(p);   // row_shr:1
    p = dpp_add<0x112, 0xf>(p);   // row_shr:2
    p = dpp_add<0x114, 0xf>(p);   // row_shr:4
    p = dpp_add<0x118, 0xf>(p);   // row_shr:8
    p = dpp_add<0x142, 0xa>(p);   // row_bcast:15
    p = dpp_add<0x143, 0xc>(p);   // row_bcast:31
    return p;
}
__device__ __forceinline__ float iscan8(float p) {       // lanes 0..7 inclusive
    p = dpp_add<0x111, 0xf>(p);
    p = dpp_add<0x112, 0xf>(p);
    p = dpp_add<0x114, 0xf>(p);
    return p;
}

// ---- pass 1: horizontal 31-box per row, fp16 output ----------------------
// Wave covers a 256-col band at 4 cols/lane. h[q] = m[s-16+q] (zero-padded),
// lane l holds q=4l..4l+3 (float4). hs[x] = Ph[x+31] - Ph[x]. High fetch is
// block l+7 (elem 3, j=0) or l+8 (elem j-1, j>=1); positions 256..286 live in
// an 8-lane ext block. 2 rows per wave for load ILP. No LDS, no barriers.
__global__ __launch_bounds__(256, 4)
void hpass_kernel(const float* __restrict__ mask, __half* __restrict__ hsum) {
    const int lane = threadIdx.x & 63;
    const int wv   = threadIdx.x >> 6;
    const int s    = blockIdx.y * 256;           // band start col
    const int row0 = blockIdx.x * 8 + wv * 2;    // global row (img*512 + y)

    const int c0 = s - 16 + 4 * lane;            // main float4 col
    const bool main_ok = (c0 >= 0);              // right side always in-range
    const int ce = s + 240 + 4 * lane;           // ext float4 col (lanes 0..7)
    const bool ext_ok = (lane < 8) && (ce + 3 < WDIM);
    const int i7 = (lane + 7) & 63, i8 = (lane + 8) & 63;

#pragma unroll
    for (int rr = 0; rr < 2; ++rr) {
        const int row = row0 + rr;
        const float* mrow = mask + (size_t)row * WDIM;

        float4 hv = make_float4(0.f, 0.f, 0.f, 0.f);
        if (main_ok) hv = *(const float4*)(mrow + c0);
        float4 ev = make_float4(0.f, 0.f, 0.f, 0.f);
        if (ext_ok)  ev = *(const float4*)(mrow + ce);

        // local inclusive prefix + coarse scan
        const float p0 = hv.x, p1 = p0 + hv.y, p2 = p1 + hv.z, p3 = p2 + hv.w;
        const float S = wave_iscan(p3);
        const float C = S - p3;
        const float S63 = __builtin_bit_cast(float,
            __builtin_amdgcn_readlane(__builtin_bit_cast(int, S), 63));
        // ext prefix (positions 256..287, lanes 0..7)
        const float e0 = ev.x, e1 = e0 + ev.y, e2 = e1 + ev.z, e3 = e2 + ev.w;
        const float Sx = iscan8(e3);
        const float Cx = S63 + Sx - e3;

        const float Ph0 = C + p0, Ph1 = C + p1, Ph2 = C + p2, Ph3 = S;
        const float X0 = Cx + e0, X1 = Cx + e1, X2 = Cx + e2, X3 = Cx + e3;

        // bpermute source registers: lanes 0..6/7 carry ext blocks 64..70/71
        const float R0 = (lane < 7) ? X3 : Ph3;
        const float R1 = (lane < 8) ? X0 : Ph0;
        const float R2 = (lane < 8) ? X1 : Ph1;
        const float R3 = (lane < 8) ? X2 : Ph2;

        const float hs0 = __shfl(R0, i7) - Ph0;
        const float hs1 = __shfl(R1, i8) - Ph1;
        const float hs2 = __shfl(R2, i8) - Ph2;
        const float hs3 = __shfl(R3, i8) - Ph3;

        __half2* op = (__half2*)(hsum + (size_t)row * WDIM + s + 4 * lane);
        op[0] = __floats2half2_rn(hs0, hs1);
        op[1] = __floats2half2_rn(hs2, hs3);
    }
}

// ---- pass 2: vertical 31-box sliding sum + elementwise + reductions ------
// Thread owns one column; vc += h[y+16] - h[y-15] with h re-read from L2/L3.
// No LDS ring, no cross-lane in the loop. 4-row-deep register prefetch.
__global__ __launch_bounds__(512, 8)
void vpass_kernel(const float* __restrict__ pred,
                  const float* __restrict__ mask,
                  const __half* __restrict__ hsum,
                  double* __restrict__ acc) {
    __shared__ float red[3][8];
    const int b    = blockIdx.x;           // image
    const int y0   = blockIdx.y * 32;      // row tile
    const int x    = threadIdx.x;          // column
    const int lane = x & 63, wv = x >> 6;

    const size_t ib = (size_t)b * HDIM * WDIM;
    const float*  mb = mask + ib;
    const float*  pb = pred + ib;
    const __half* hb = hsum + ib;

    // warmup: vc = sum of hsum rows y0-15 .. y0+15 (clamped low; high <512)
    float vc = 0.f;
    {
        int lo = y0 - 15; if (lo < 0) lo = 0;
        const int hi = y0 + 15;
        for (int r = lo; r <= hi; ++r)
            vc += __half2float(hb[(size_t)r * WDIM + x]);
    }

    float bce = 0.f, inter = 0.f, uni = 0.f;

    auto ldh = [&](int r) -> float {
        return ((unsigned)r < (unsigned)HDIM)
            ? __half2float(hb[(size_t)r * WDIM + x]) : 0.f;
    };
    auto ldrow = [&](int y, float& M, float& P, float& A, float& Sv) {
        if (y < y0 + 32) {                         // wave-uniform guard
            const size_t o = (size_t)y * WDIM + x;
            M = mb[o]; P = pb[o];
            A = ldh(y + 16); Sv = ldh(y - 15);
        } else { M = 0.f; P = 0.f; A = 0.f; Sv = 0.f; }
    };
    auto emit = [&](float M, float P, float vsv) {
        const float box  = vsv * INV_KK;
        const float weit = 1.f + 5.f * fabsf(box - M);
        const float e1   = __expf(-fabsf(P));
        const float den  = __builtin_amdgcn_rcpf(1.f + e1);
        const float sp   = ((P >= 0.f) ? 1.f : e1) * den;   // sigmoid(P)
        bce   += fmaxf(P, 0.f) - P * M + __logf(1.f + e1);
        inter += sp * M * weit;
        uni   += (sp + M) * weit;
    };

    float cm0,cp0,ca0,cs0, cm1,cp1,ca1,cs1;
    float nm0,np0,na0,ns0, nm1,np1,na1,ns1;
    ldrow(y0,     cm0,cp0,ca0,cs0);
    ldrow(y0 + 1, cm1,cp1,ca1,cs1);
    ldrow(y0 + 2, nm0,np0,na0,ns0);
    ldrow(y0 + 3, nm1,np1,na1,ns1);

#pragma unroll 2
    for (int y = y0; y < y0 + 32; y += 2) {
        float fm0,fp0,fa0,fs0, fm1,fp1,fa1,fs1;
        ldrow(y + 4, fm0,fp0,fa0,fs0);
        ldrow(y + 5, fm1,fp1,fa1,fs1);

        emit(cm0, cp0, vc);  vc += ca0 - cs0;
        emit(cm1, cp1, vc);  vc += ca1 - cs1;

        cm0=nm0; cp0=np0; ca0=na0; cs0=ns0;
        cm1=nm1; cp1=np1; ca1=na1; cs1=ns1;
        nm0=fm0; np0=fp0; na0=fa0; ns0=fs0;
        nm1=fm1; np1=fp1; na1=fa1; ns1=fs1;
    }

    // ---- block reduction (8 waves) ----
#pragma unroll
    for (int off = 32; off > 0; off >>= 1) {
        bce   += __shfl_down(bce, off);
        inter += __shfl_down(inter, off);
        uni   += __shfl_down(uni, off);
    }
    if (lane == 0) { red[0][wv] = bce; red[1][wv] = inter; red[2][wv] = uni; }
    __syncthreads();
    if (threadIdx.x == 0) {
        float bs = 0.f, is = 0.f, us = 0.f;
#pragma unroll
        for (int w = 0; w < 8; ++w) { bs += red[0][w]; is += red[1][w]; us += red[2][w]; }
        atomicAdd(&acc[0],      (double)bs);
        atomicAdd(&acc[1 + b],  (double)is);
        atomicAdd(&acc[65 + b], (double)us);
    }
}

__global__ void finalize_kernel(const double* __restrict__ acc, float* __restrict__ out) {
    const int b = threadIdx.x;   // one wave
    double inter = acc[1 + b];
    double uni   = acc[65 + b];
    double wiou  = 1.0 - (inter + 1.0) / (uni - inter + 1.0);
#pragma unroll
    for (int off = 32; off > 0; off >>= 1) wiou += __shfl_down(wiou, off);
    if (b == 0) {
        double wbce = acc[0] / (double)NPIX;
        out[0] = (float)(wbce + wiou / (double)BDIM);
    }
}

extern "C" void kernel_launch(void* const* d_in, const int* in_sizes, int n_in,
                              void* d_out, int out_size, void* d_ws, size_t ws_size,
                              hipStream_t stream) {
    const float* pred = (const float*)d_in[0];
    const float* mask = (const float*)d_in[1];
    float* out = (float*)d_out;

    __half* hsum = (__half*)d_ws;                         // 33.5 MiB
    double* acc  = (double*)((char*)d_ws + NPIX * sizeof(__half));

    zero_acc_kernel<<<1, 256, 0, stream>>>(acc);

    // pass 1: 64*512 rows, 2 bands; 4 waves x 2 rows per block
    dim3 g1((BDIM * HDIM) / 8, 2);
    hpass_kernel<<<g1, 256, 0, stream>>>(mask, hsum);

    // pass 2: 64 images x 16 row-tiles; 512 threads = 1 col each
    dim3 g2(BDIM, HDIM / 32);
    vpass_kernel<<<g2, 512, 0, stream>>>(pred, mask, hsum, acc);

    finalize_kernel<<<1, 64, 0, stream>>>(acc, out);
}